// Round 1
// baseline (1374.181 us; speedup 1.0000x reference)
//
#include <hip/hip_runtime.h>
#include <hip/hip_bf16.h>

#define DE 100
#define RK 40
#define NENT 10000
#define BATCH 128
#define KDIM 1600          // 40*40
#define MN 10000           // 100*100
#define PRED_SIZE (BATCH*NENT)

typedef __bf16 bf16x8 __attribute__((ext_vector_type(8)));
typedef float floatx4 __attribute__((ext_vector_type(4)));

// RTNE float -> bf16 bits (manual, avoids header API differences)
static __device__ __forceinline__ unsigned short f2bf(float f) {
    unsigned int u = __builtin_bit_cast(unsigned int, f);
    unsigned int lsb = (u >> 16) & 1u;
    u += 0x7fffu + lsb;
    return (unsigned short)(u >> 16);
}

// ---------------- prep_A: A'[m=(i,j)][e=(a*40+c)] = sum_b f0[a,i,b] f1[b,j,c] ----------------
__global__ void prep_A_kernel(const float* __restrict__ f0, const float* __restrict__ f1,
                              unsigned short* __restrict__ Abf) {
    const int m = blockIdx.x;          // i*100 + j
    const int i = m / 100, j = m % 100;
    const int t = threadIdx.x;
    __shared__ __align__(16) float P[KDIM];  // F0[a*40+b]
    __shared__ __align__(16) float Q[KDIM];  // F1[b*40+c]
    for (int e = t; e < KDIM; e += 256) {
        const int u = e / 40, v = e % 40;
        P[e] = f0[u*4000 + i*40 + v];
        Q[e] = f1[u*4000 + j*40 + v];
    }
    __syncthreads();
    for (int o = t; o < 400; o += 256) {
        const int x  = o / 10;          // a
        const int z4 = (o % 10) * 4;    // c base
        float a0=0.f, a1=0.f, a2=0.f, a3=0.f;
        #pragma unroll
        for (int y = 0; y < 40; ++y) {
            const float s = P[x*40 + y];
            const float4 q = *reinterpret_cast<const float4*>(&Q[y*40 + z4]);
            a0 += s*q.x; a1 += s*q.y; a2 += s*q.z; a3 += s*q.w;
        }
        ushort4 r;
        r.x = f2bf(a0); r.y = f2bf(a1); r.z = f2bf(a2); r.w = f2bf(a3);
        *reinterpret_cast<ushort4*>(&Abf[(size_t)m*KDIM + x*40 + z4]) = r;
    }
}

// ---------------- prep_B: B'[n=(k,l)][e=(a*40+c)] = sum_d f2[c,k,d] f3[d,l,a] ----------------
__global__ void prep_B_kernel(const float* __restrict__ f2, const float* __restrict__ f3,
                              unsigned short* __restrict__ Bbf) {
    const int n = blockIdx.x;          // k*100 + l
    const int k = n / 100, l = n % 100;
    const int t = threadIdx.x;
    __shared__ __align__(16) float P[KDIM];   // F2[c*40+d]
    __shared__ __align__(16) float Q[KDIM];   // F3[d*40+a]
    __shared__ __align__(16) float Rt[KDIM];  // R[c*40+a]
    for (int e = t; e < KDIM; e += 256) {
        const int u = e / 40, v = e % 40;
        P[e] = f2[u*4000 + k*40 + v];
        Q[e] = f3[u*4000 + l*40 + v];
    }
    __syncthreads();
    for (int o = t; o < 400; o += 256) {
        const int x  = o / 10;          // c
        const int z4 = (o % 10) * 4;    // a base
        float a0=0.f, a1=0.f, a2=0.f, a3=0.f;
        #pragma unroll
        for (int y = 0; y < 40; ++y) {
            const float s = P[x*40 + y];
            const float4 q = *reinterpret_cast<const float4*>(&Q[y*40 + z4]);
            a0 += s*q.x; a1 += s*q.y; a2 += s*q.z; a3 += s*q.w;
        }
        Rt[x*40 + z4 + 0] = a0; Rt[x*40 + z4 + 1] = a1;
        Rt[x*40 + z4 + 2] = a2; Rt[x*40 + z4 + 3] = a3;
    }
    __syncthreads();
    // transpose-store: B'[n][a*40+c] = Rt[c*40+a]
    for (int o = t; o < 400; o += 256) {
        const int a  = o / 10;
        const int c4 = (o % 10) * 4;
        ushort4 r;
        r.x = f2bf(Rt[(c4+0)*40 + a]);
        r.y = f2bf(Rt[(c4+1)*40 + a]);
        r.z = f2bf(Rt[(c4+2)*40 + a]);
        r.w = f2bf(Rt[(c4+3)*40 + a]);
        *reinterpret_cast<ushort4*>(&Bbf[(size_t)n*KDIM + a*40 + c4]) = r;
    }
}

// ---------------- GEMM: W[m][n] = sum_e A'[m][e] * B'[n][e]  (m97-style) ----------------
typedef __attribute__((address_space(1))) void gvoid;
typedef __attribute__((address_space(3))) void lvoid;
static __device__ __forceinline__ void async_cp16(const void* g, void* l) {
    gvoid* gp = (gvoid*)(unsigned long long)g;
    lvoid* lp = (lvoid*)(unsigned int)(unsigned long long)l;
    __builtin_amdgcn_global_load_lds(gp, lp, 16, 0, 0);
}

__global__ __launch_bounds__(256) void gemm_kernel(const unsigned short* __restrict__ A,
                                                   const unsigned short* __restrict__ Bm,
                                                   float* __restrict__ W) {
    __shared__ __align__(16) unsigned short As[4096];  // [128][32]
    __shared__ __align__(16) unsigned short Bs[4096];  // [128][32]
    const int t = threadIdx.x;
    const int w = t >> 6, l = t & 63;
    const int wm = w >> 1, wn = w & 1;
    const int quad = l >> 4, lrow = l & 15;
    const int m0 = blockIdx.y * 128, n0 = blockIdx.x * 128;

    const int srow = t >> 2;           // 0..63
    const int scol = (t & 3) * 8;      // 0,8,16,24
    const int rA0 = (m0 + srow      < MN) ? (m0 + srow)      : (MN-1);
    const int rA1 = (m0 + 64 + srow < MN) ? (m0 + 64 + srow) : (MN-1);
    const int rB0 = (n0 + srow      < MN) ? (n0 + srow)      : (MN-1);
    const int rB1 = (n0 + 64 + srow < MN) ? (n0 + 64 + srow) : (MN-1);
    const unsigned short* gA0 = A  + (size_t)rA0*KDIM + scol;
    const unsigned short* gA1 = A  + (size_t)rA1*KDIM + scol;
    const unsigned short* gB0 = Bm + (size_t)rB0*KDIM + scol;
    const unsigned short* gB1 = Bm + (size_t)rB1*KDIM + scol;
    unsigned short* lA0 = &As[w*512];
    unsigned short* lA1 = &As[2048 + w*512];
    unsigned short* lB0 = &Bs[w*512];
    unsigned short* lB1 = &Bs[2048 + w*512];

    floatx4 acc[4][4] = {};

    for (int k0 = 0; k0 < KDIM; k0 += 32) {
        async_cp16(gA0 + k0, lA0);
        async_cp16(gA1 + k0, lA1);
        async_cp16(gB0 + k0, lB0);
        async_cp16(gB1 + k0, lB1);
        __syncthreads();
        bf16x8 af[4], bfv[4];
        #pragma unroll
        for (int mi = 0; mi < 4; ++mi)
            af[mi] = *reinterpret_cast<const bf16x8*>(&As[(wm*64 + mi*16 + lrow)*32 + quad*8]);
        #pragma unroll
        for (int ni = 0; ni < 4; ++ni)
            bfv[ni] = *reinterpret_cast<const bf16x8*>(&Bs[(wn*64 + ni*16 + lrow)*32 + quad*8]);
        #pragma unroll
        for (int mi = 0; mi < 4; ++mi) {
            #pragma unroll
            for (int ni = 0; ni < 4; ++ni)
                acc[mi][ni] = __builtin_amdgcn_mfma_f32_16x16x32_bf16(af[mi], bfv[ni], acc[mi][ni], 0, 0, 0);
        }
        __syncthreads();
    }

    #pragma unroll
    for (int mi = 0; mi < 4; ++mi) {
        #pragma unroll
        for (int ni = 0; ni < 4; ++ni) {
            #pragma unroll
            for (int reg = 0; reg < 4; ++reg) {
                const int rg = m0 + wm*64 + mi*16 + quad*4 + reg;
                const int cg = n0 + wn*64 + ni*16 + lrow;
                if (rg < MN && cg < MN)
                    W[(size_t)rg * MN + cg] = acc[mi][ni][reg];
            }
        }
    }
}

// ---------------- BatchNorm1d (training-mode batch stats), optional gather ----------------
__global__ void bn_kernel(const float* __restrict__ src, const int* __restrict__ idx,
                          const float* __restrict__ gamma, const float* __restrict__ beta,
                          float* __restrict__ out) {
    const int f = blockIdx.x;       // feature 0..99
    const int b = threadIdx.x;      // 0..127
    __shared__ float red[BATCH];
    const int row = idx ? idx[b] : b;
    const float x = src[row*DE + f];
    red[b] = x; __syncthreads();
    for (int s = 64; s > 0; s >>= 1) { if (b < s) red[b] += red[b + s]; __syncthreads(); }
    const float mu = red[0] * (1.0f/BATCH);
    __syncthreads();
    const float d = x - mu;
    red[b] = d * d; __syncthreads();
    for (int s = 64; s > 0; s >>= 1) { if (b < s) red[b] += red[b + s]; __syncthreads(); }
    const float var = red[0] * (1.0f/BATCH);
    out[b*DE + f] = gamma[f] * d / sqrtf(var + 1e-5f) + beta[f];
}

// ---------------- per-batch factored contraction -> W_out_raw[b][j] ----------------
__global__ void proj_kernel(const float* __restrict__ rb, const float* __restrict__ e1b,
                            const float* __restrict__ e2b,
                            const float* __restrict__ f0, const float* __restrict__ f1,
                            const float* __restrict__ f2, const float* __restrict__ f3,
                            float* __restrict__ wraw) {
    const int b = blockIdx.x, t = threadIdx.x;
    __shared__ float rv[DE], e1v[DE], e2v[DE];
    __shared__ float R0[KDIM], E1[KDIM], E2[KDIM], T[KDIM], S[KDIM];
    if (t < DE) { rv[t] = rb[b*DE+t]; e1v[t] = e1b[b*DE+t]; e2v[t] = e2b[b*DE+t]; }
    __syncthreads();
    // R0[a,be] = sum_p r[p] f0[a,p,be]; E1[be,c] = sum_i e1[i] f1[be,i,c]; E2[d,a] = sum_k e2[k] f3[d,k,a]
    for (int e = t; e < KDIM; e += 256) {
        const int u = e / 40, v = e % 40;
        const int base = u*4000 + v;
        float aR=0.f, aE1=0.f, aE2=0.f;
        for (int p = 0; p < DE; ++p) {
            aR  += rv[p]  * f0[base + p*40];
            aE1 += e1v[p] * f1[base + p*40];
            aE2 += e2v[p] * f3[base + p*40];
        }
        R0[e] = aR; E1[e] = aE1; E2[e] = aE2;
    }
    __syncthreads();
    // T[a,c] = sum_be R0[a,be] E1[be,c]
    for (int e = t; e < KDIM; e += 256) {
        const int a = e / 40, c = e % 40;
        float acc = 0.f;
        #pragma unroll
        for (int y = 0; y < 40; ++y) acc += R0[a*40+y] * E1[y*40+c];
        T[e] = acc;
    }
    __syncthreads();
    // S[c,d] = sum_a T[a,c] E2[d,a]
    for (int e = t; e < KDIM; e += 256) {
        const int c = e / 40, d = e % 40;
        float acc = 0.f;
        #pragma unroll
        for (int y = 0; y < 40; ++y) acc += T[y*40+c] * E2[d*40+y];
        S[e] = acc;
    }
    __syncthreads();
    // wraw[b,j] = sum_{c,d} S[c,d] f2[c,j,d]
    if (t < DE) {
        float acc = 0.f;
        for (int c = 0; c < 40; ++c) {
            #pragma unroll
            for (int d = 0; d < 40; ++d)
                acc += S[c*40+d] * f2[c*4000 + t*40 + d];
        }
        wraw[b*DE + t] = acc;
    }
}

// ---------------- scores: out[b][n] = dot(wbn[b], E[n]) (raw scores into pred region) ----------
__global__ void scores_kernel(const float* __restrict__ wbn, const float* __restrict__ E,
                              float* __restrict__ scores) {
    const int bx = blockIdx.x;
    const int b = bx >> 3, chunk = bx & 7;
    const int t = threadIdx.x;
    __shared__ __align__(16) float wsh[DE];
    if (t < DE) wsh[t] = wbn[b*DE + t];
    __syncthreads();
    const float4* wv = reinterpret_cast<const float4*>(wsh);
    const int n_end = (chunk + 1) * 1250;
    for (int n = chunk*1250 + t; n < n_end; n += 256) {
        const float4* er = reinterpret_cast<const float4*>(E + (size_t)n * DE);
        float acc = 0.f;
        #pragma unroll
        for (int q = 0; q < 25; ++q) {
            const float4 e4 = er[q], w4 = wv[q];
            acc += e4.x*w4.x + e4.y*w4.y + e4.z*w4.z + e4.w*w4.w;
        }
        scores[(size_t)b*NENT + n] = acc;
    }
}

__global__ void softmax_reduce_kernel(const float* __restrict__ scores,
                                      float* __restrict__ rmax, float* __restrict__ rsum) {
    const int b = blockIdx.x, t = threadIdx.x;
    __shared__ float red[256];
    const float* s = scores + (size_t)b*NENT;
    float m = -1e30f;
    for (int n = t; n < NENT; n += 256) m = fmaxf(m, s[n]);
    red[t] = m; __syncthreads();
    for (int st = 128; st > 0; st >>= 1) { if (t < st) red[t] = fmaxf(red[t], red[t+st]); __syncthreads(); }
    m = red[0]; __syncthreads();
    float sum = 0.f;
    for (int n = t; n < NENT; n += 256) sum += expf(s[n] - m);
    red[t] = sum; __syncthreads();
    for (int st = 128; st > 0; st >>= 1) { if (t < st) red[t] += red[t+st]; __syncthreads(); }
    if (t == 0) { rmax[b] = m; rsum[b] = red[0]; }
}

__global__ void pred_kernel(float* __restrict__ out, const float* __restrict__ rmax,
                            const float* __restrict__ rsum) {
    const int i = blockIdx.x*256 + threadIdx.x;
    const int b = i / NENT;
    out[i] = expf(out[i] - rmax[b]) / rsum[b];
}

extern "C" void kernel_launch(void* const* d_in, const int* in_sizes, int n_in,
                              void* d_out, int out_size, void* d_ws, size_t ws_size,
                              hipStream_t stream) {
    (void)in_sizes; (void)n_in; (void)out_size; (void)ws_size;
    const float* E    = (const float*)d_in[0];
    const float* Rw   = (const float*)d_in[1];
    const float* f0   = (const float*)d_in[2];
    const float* f1   = (const float*)d_in[3];
    const float* f2   = (const float*)d_in[4];
    const float* f3   = (const float*)d_in[5];
    const float* bnrg = (const float*)d_in[6];
    const float* bnrb = (const float*)d_in[7];
    const float* bneg = (const float*)d_in[8];
    const float* bneb = (const float*)d_in[9];
    const float* bnwg = (const float*)d_in[10];
    const float* bnwb = (const float*)d_in[11];
    const int* r_idx  = (const int*)d_in[12];
    const int* e_idx1 = (const int*)d_in[13];
    const int* e_idx2 = (const int*)d_in[14];
    // d_in[15] = miss_ent_domain, fixed at 2 for this problem's setup (eq: bijk,bi,bk->bj)

    float* out = (float*)d_out;
    float* Wt  = out + PRED_SIZE;       // W region: 1e8 floats

    char* ws = (char*)d_ws;
    unsigned short* Abf = (unsigned short*)ws;                  // 32 MB
    unsigned short* Bbf = (unsigned short*)(ws + 32000000);     // 32 MB
    float* rbn  = (float*)(ws + 64000000);
    float* e1bn = rbn  + BATCH*DE;
    float* e2bn = e1bn + BATCH*DE;
    float* wraw = e2bn + BATCH*DE;
    float* wbn  = wraw + BATCH*DE;
    float* rmax = wbn  + BATCH*DE;
    float* rsum = rmax + BATCH;

    prep_A_kernel<<<MN, 256, 0, stream>>>(f0, f1, Abf);
    prep_B_kernel<<<MN, 256, 0, stream>>>(f2, f3, Bbf);
    gemm_kernel<<<dim3(79, 79), 256, 0, stream>>>(Abf, Bbf, Wt);

    bn_kernel<<<DE, BATCH, 0, stream>>>(Rw, r_idx, bnrg, bnrb, rbn);
    bn_kernel<<<DE, BATCH, 0, stream>>>(E, e_idx1, bneg, bneb, e1bn);
    bn_kernel<<<DE, BATCH, 0, stream>>>(E, e_idx2, bneg, bneb, e2bn);
    proj_kernel<<<BATCH, 256, 0, stream>>>(rbn, e1bn, e2bn, f0, f1, f2, f3, wraw);
    bn_kernel<<<DE, BATCH, 0, stream>>>(wraw, nullptr, bnwg, bnwb, wbn);
    scores_kernel<<<BATCH*8, 256, 0, stream>>>(wbn, E, out);
    softmax_reduce_kernel<<<BATCH, 256, 0, stream>>>(out, rmax, rsum);
    pred_kernel<<<PRED_SIZE/256, 256, 0, stream>>>(out, rmax, rsum);
}